// Round 1
// baseline (343.873 us; speedup 1.0000x reference)
//
#include <hip/hip_runtime.h>

#define D 512
#define D4 (D / 4)
#define MAXC 256
#define FEPS 1e-12f
#define FBIG 3.0e38f
#define DROWS 8

__device__ __forceinline__ float wave_rsum(float v) {
#pragma unroll
    for (int o = 32; o > 0; o >>= 1) v += __shfl_down(v, o);
    return v;
}

// --- 1. row L2-normalize; also a2[i] = sum(y^2) of the normalized row ---
__global__ void k_normalize(const float* __restrict__ emb, float* __restrict__ embn,
                            float* __restrict__ a2) {
    const int i = blockIdx.x;
    const int tid = threadIdx.x;  // 128 threads, float4 each
    __shared__ float red[2];
    const float4 x = ((const float4*)(emb + (size_t)i * D))[tid];
    float ss = x.x * x.x + x.y * x.y + x.z * x.z + x.w * x.w;
    ss = wave_rsum(ss);
    if ((tid & 63) == 0) red[tid >> 6] = ss;
    __syncthreads();
    const float tot = red[0] + red[1];
    const float inv = 1.0f / fmaxf(sqrtf(tot), FEPS);
    const float4 y = make_float4(x.x * inv, x.y * inv, x.z * inv, x.w * inv);
    ((float4*)(embn + (size_t)i * D))[tid] = y;
    float s2 = y.x * y.x + y.y * y.y + y.z * y.z + y.w * y.w;
    s2 = wave_rsum(s2);
    __syncthreads();
    if ((tid & 63) == 0) red[tid >> 6] = s2;
    __syncthreads();
    if (tid == 0) a2[i] = red[0] + red[1];
}

// --- 2a. class histogram ---
__global__ void k_count(const int* __restrict__ t, int* __restrict__ ccount, int n) {
    const int i = blockIdx.x * blockDim.x + threadIdx.x;
    if (i < n) atomicAdd(&ccount[t[i]], 1);
}

// --- 2b. exclusive prefix over classes ---
__global__ void k_scan(const int* __restrict__ ccount, int* __restrict__ coff,
                       const int* __restrict__ ncls) {
    __shared__ int lc[MAXC];
    const int C = *ncls;
    for (int c = threadIdx.x; c < C; c += blockDim.x) lc[c] = ccount[c];
    __syncthreads();
    if (threadIdx.x == 0) {
        int s = 0;
        for (int c = 0; c < C; ++c) { coff[c] = s; s += lc[c]; }
        coff[C] = s;
    }
}

// --- 2c. deterministic (index-ordered) per-class row lists ---
__global__ void k_build(const int* __restrict__ t, const int* __restrict__ coff,
                        int* __restrict__ clist, int n, const int* __restrict__ ncls) {
    const int C = *ncls;
    __shared__ int wtot[4];
    for (int c = blockIdx.x; c < C; c += gridDim.x) {
        int base = coff[c];
        for (int start = 0; start < n; start += 256) {
            const int j = start + (int)threadIdx.x;
            const bool flag = (j < n) && (t[j] == c);
            const unsigned long long m = __ballot(flag);
            const int lane = threadIdx.x & 63;
            const int w = threadIdx.x >> 6;
            const int pre = __popcll(m & ((1ull << lane) - 1ull));
            if (lane == 0) wtot[w] = __popcll(m);
            __syncthreads();
            int woff = 0;
            for (int k = 0; k < w; ++k) woff += wtot[k];
            const int tot = wtot[0] + wtot[1] + wtot[2] + wtot[3];
            if (flag) clist[base + woff + pre] = j;
            base += tot;
            __syncthreads();
        }
    }
}

// --- 3. class centers + cc2[c] = sum(center^2) ---
__global__ void k_centers(const float* __restrict__ embn, const int* __restrict__ clist,
                          const int* __restrict__ coff, const int* __restrict__ ccount,
                          float* __restrict__ centers, float* __restrict__ cc2,
                          const int* __restrict__ ncls) {
    const int C = *ncls;
    __shared__ float wsum[4];
    for (int c = blockIdx.x; c < C; c += gridDim.x) {
        const int off = coff[c], cnt = ccount[c];
        const float denom = fmaxf((float)cnt, 1e-6f);
        float ss = 0.f;
        for (int k = threadIdx.x; k < D; k += 256) {
            float s = 0.f;
            for (int m = 0; m < cnt; ++m) {
                const int j = clist[off + m];
                s += embn[(size_t)j * D + k];
            }
            const float v = s / denom;
            centers[(size_t)c * D + k] = v;
            ss += v * v;
        }
        ss = wave_rsum(ss);
        if ((threadIdx.x & 63) == 0) wsum[threadIdx.x >> 6] = ss;
        __syncthreads();
        if (threadIdx.x == 0) cc2[c] = wsum[0] + wsum[1] + wsum[2] + wsum[3];
        __syncthreads();
    }
}

// --- 4. d_neg_min: 8 rows per block, one thread per class ---
__global__ void k_dneg(const float* __restrict__ embn, const float* __restrict__ a2,
                       const int* __restrict__ t, const float* __restrict__ centers,
                       const float* __restrict__ cc2, float* __restrict__ dneg,
                       int n, const int* __restrict__ ncls) {
    const int C = *ncls;
    const int i0 = blockIdx.x * DROWS;
    __shared__ __align__(16) float lrow[DROWS][D];
    __shared__ float la2[DROWS];
    __shared__ int lt[DROWS];
    __shared__ float mins[DROWS][128];
#pragma unroll
    for (int r = 0; r < DROWS; ++r) {
        if (i0 + r < n)
            ((float4*)lrow[r])[threadIdx.x] =
                ((const float4*)(embn + (size_t)(i0 + r) * D))[threadIdx.x];
    }
    if (threadIdx.x < DROWS) {
        const int ii = i0 + (int)threadIdx.x;
        la2[threadIdx.x] = (ii < n) ? a2[ii] : 0.f;
        lt[threadIdx.x] = (ii < n) ? t[ii] : -1;
    }
    __syncthreads();
    const int c = threadIdx.x;
    float best[DROWS];
    if (c < C) {
        float acc[DROWS];
#pragma unroll
        for (int r = 0; r < DROWS; ++r) acc[r] = 0.f;
        const float4* cp = (const float4*)(centers + (size_t)c * D);
        for (int k = 0; k < D4; ++k) {
            const float4 cv = cp[k];
#pragma unroll
            for (int r = 0; r < DROWS; ++r) {
                const float4 ev = ((const float4*)lrow[r])[k];
                acc[r] += cv.x * ev.x + cv.y * ev.y + cv.z * ev.z + cv.w * ev.w;
            }
        }
        const float c2 = cc2[c];
#pragma unroll
        for (int r = 0; r < DROWS; ++r) {
            const float sq = la2[r] + c2 - 2.f * acc[r];
            float dv = sqrtf(fmaxf(sq, FEPS));
            if (lt[r] == c) dv = FBIG;
            best[r] = dv;
        }
    } else {
#pragma unroll
        for (int r = 0; r < DROWS; ++r) best[r] = FBIG;
    }
#pragma unroll
    for (int r = 0; r < DROWS; ++r) mins[r][threadIdx.x] = best[r];
    __syncthreads();
    for (int s = 64; s > 0; s >>= 1) {
        if (threadIdx.x < s) {
#pragma unroll
            for (int r = 0; r < DROWS; ++r)
                mins[r][threadIdx.x] = fminf(mins[r][threadIdx.x], mins[r][threadIdx.x + s]);
        }
        __syncthreads();
    }
    if (threadIdx.x < DROWS && i0 + (int)threadIdx.x < n)
        dneg[i0 + threadIdx.x] = mins[threadIdx.x][0];
}

// --- 5. top-3 hardest positives + d_pos, block per row ---
__global__ void k_topk(const float* __restrict__ embn, const float* __restrict__ a2,
                       const int* __restrict__ t, const int* __restrict__ clist,
                       const int* __restrict__ coff, const int* __restrict__ ccount,
                       float* __restrict__ dpos, float* __restrict__ dvalid) {
    const int i = blockIdx.x;
    const int tid = threadIdx.x;  // 128
    __shared__ __align__(16) float ei[D];
    __shared__ float sa2i;
    __shared__ int soff, scnt;
    ((float4*)ei)[tid] = ((const float4*)(embn + (size_t)i * D))[tid];
    if (tid == 0) {
        sa2i = a2[i];
        const int c = t[i];
        soff = coff[c];
        scnt = ccount[c];
    }
    __syncthreads();
    const float a2i = sa2i;
    const int off = soff, cnt = scnt;

    // per-thread top-3 over a strided slice of the class list (squared dist, pre-sqrt)
    float tv0 = -FBIG, tv1 = -FBIG, tv2 = -FBIG;
    int tj0 = -1, tj1 = -1, tj2 = -1;
    for (int m = tid; m < cnt; m += 128) {
        const int j = clist[off + m];
        if (j == i) continue;
        const float4* bp = (const float4*)(embn + (size_t)j * D);
        float dot = 0.f;
#pragma unroll 8
        for (int k = 0; k < D4; ++k) {
            const float4 a = ((const float4*)ei)[k];
            const float4 b = bp[k];
            dot += a.x * b.x + a.y * b.y + a.z * b.z + a.w * b.w;
        }
        const float sq = a2i + a2[j] - 2.f * dot;
        if (sq > tv0)      { tv2 = tv1; tj2 = tj1; tv1 = tv0; tj1 = tj0; tv0 = sq; tj0 = j; }
        else if (sq > tv1) { tv2 = tv1; tj2 = tj1; tv1 = sq; tj1 = j; }
        else if (sq > tv2) { tv2 = sq; tj2 = j; }
    }

    // 3-round block argmax (tie-break: smaller row index, matching top_k order)
    __shared__ float bval[128];
    __shared__ int bidx[128];
    __shared__ int winj[3];
    int p = 0;
    for (int r = 0; r < 3; ++r) {
        const float curv = (p == 0) ? tv0 : ((p == 1) ? tv1 : ((p == 2) ? tv2 : -FBIG));
        const int curj = (p == 0) ? tj0 : ((p == 1) ? tj1 : ((p == 2) ? tj2 : -1));
        bval[tid] = curv;
        bidx[tid] = curj;
        __syncthreads();
        for (int s = 64; s > 0; s >>= 1) {
            if (tid < s) {
                const float v2 = bval[tid + s]; const int j2 = bidx[tid + s];
                const float v1 = bval[tid];     const int j1 = bidx[tid];
                if (j2 != -1 && (j1 == -1 || v2 > v1 || (v2 == v1 && j2 < j1))) {
                    bval[tid] = v2; bidx[tid] = j2;
                }
            }
            __syncthreads();
        }
        if (tid == 0) winj[r] = bidx[0];
        __syncthreads();
        if (curj != -1 && curj == winj[r]) p++;  // owner pops its candidate
    }

    const int w0 = winj[0], w1 = winj[1], w2 = winj[2];
    const int nw = (w0 != -1) + (w1 != -1) + (w2 != -1);
    float accp = 0.f;
    if (nw > 0) {
        const int jA = w0;
        const int jB = (w1 != -1) ? w1 : jA;
        const int jC = (w2 != -1) ? w2 : jB;
        for (int k = tid; k < D; k += 128) {
            const float cen = (embn[(size_t)jA * D + k] + embn[(size_t)jB * D + k] +
                               embn[(size_t)jC * D + k]) * (1.0f / 3.0f);
            const float df = ei[k] - cen;
            accp += df * df;
        }
    }
    accp = wave_rsum(accp);
    __shared__ float red2[2];
    if ((tid & 63) == 0) red2[tid >> 6] = accp;
    __syncthreads();
    if (tid == 0) {
        const float s = red2[0] + red2[1];
        dpos[i] = sqrtf(fmaxf(s, FEPS));
        dvalid[i] = (nw > 0) ? 1.0f : 0.0f;
    }
}

// --- 6. stable softplus + masked mean ---
__global__ void k_loss(const float* __restrict__ dpos, const float* __restrict__ dneg,
                       const float* __restrict__ dvalid, float* __restrict__ accum, int n) {
    const int i = blockIdx.x * blockDim.x + threadIdx.x;
    float l = 0.f, v = 0.f;
    if (i < n) {
        v = dvalid[i];
        const float x = dpos[i] - dneg[i];
        const float sp = fmaxf(x, 0.f) + log1pf(expf(-fabsf(x)));
        l = sp * v;
    }
    l = wave_rsum(l);
    v = wave_rsum(v);
    __shared__ float wl[4], wv[4];
    const int lane = threadIdx.x & 63, w = threadIdx.x >> 6;
    if (lane == 0) { wl[w] = l; wv[w] = v; }
    __syncthreads();
    if (threadIdx.x == 0) {
        atomicAdd(&accum[0], wl[0] + wl[1] + wl[2] + wl[3]);
        atomicAdd(&accum[1], wv[0] + wv[1] + wv[2] + wv[3]);
    }
}

__global__ void k_final(const float* __restrict__ accum, float* __restrict__ out) {
    out[0] = accum[0] / fmaxf(accum[1], 1.0f);
}

extern "C" void kernel_launch(void* const* d_in, const int* in_sizes, int n_in,
                              void* d_out, int out_size, void* d_ws, size_t ws_size,
                              hipStream_t stream) {
    const float* emb = (const float*)d_in[0];
    const int* targets = (const int*)d_in[1];
    const int* ncls = (const int*)d_in[2];
    const int n = in_sizes[1];  // 8192; d = in_sizes[0]/n = 512 (compile-time D)

    float* fp = (float*)d_ws;
    float* embn = fp;    fp += (size_t)n * D;
    float* a2 = fp;      fp += n;
    float* centers = fp; fp += (size_t)MAXC * D;
    float* cc2 = fp;     fp += MAXC;
    float* dneg = fp;    fp += n;
    float* dpos = fp;    fp += n;
    float* dvalid = fp;  fp += n;
    float* accum = fp;   fp += 2;
    int* ccount = (int*)fp; fp += MAXC;
    int* coff = (int*)fp;   fp += MAXC + 1;
    int* clist = (int*)fp;  fp += n;

    hipMemsetAsync(ccount, 0, MAXC * sizeof(int), stream);
    hipMemsetAsync(accum, 0, 2 * sizeof(float), stream);

    k_normalize<<<n, 128, 0, stream>>>(emb, embn, a2);
    k_count<<<(n + 255) / 256, 256, 0, stream>>>(targets, ccount, n);
    k_scan<<<1, 256, 0, stream>>>(ccount, coff, ncls);
    k_build<<<128, 256, 0, stream>>>(targets, coff, clist, n, ncls);
    k_centers<<<128, 256, 0, stream>>>(embn, clist, coff, ccount, centers, cc2, ncls);
    k_dneg<<<(n + DROWS - 1) / DROWS, 128, 0, stream>>>(embn, a2, targets, centers, cc2, dneg, n, ncls);
    k_topk<<<n, 128, 0, stream>>>(embn, a2, targets, clist, coff, ccount, dpos, dvalid);
    k_loss<<<(n + 255) / 256, 256, 0, stream>>>(dpos, dneg, dvalid, accum, n);
    k_final<<<1, 1, 0, stream>>>(accum, (float*)d_out);
}